// Round 15
// baseline (26940.576 us; speedup 1.0000x reference)
//
#include <hip/hip_runtime.h>
#include <stdint.h>

typedef short short8 __attribute__((ext_vector_type(8)));
typedef float f32x4 __attribute__((ext_vector_type(4)));
typedef unsigned short u16;

#define MFMA16(a, b, c) __builtin_amdgcn_mfma_f32_16x16x32_bf16((a), (b), (c), 0, 0, 0)
#define SINK(x) asm volatile("" :: "v"(x))

#define T_LEN 512
#define BATCH 64
#define EMB_D 512
#define HID 1024
#define VOC 256
#define NWG 128
#define RNN_THREADS 512
#define R0 256
#define R1 8
#define SLOT (BATCH * HID)

// -------- workspace layout (bytes) --------
#define OFF_XT    0u
#define OFF_EMBT  131072u
#define OFF_WIH0  524288u
#define OFF_WHH0  3670016u
#define OFF_WIH1  9961472u
#define OFF_WHH1  16252928u
#define OFF_WOUT  22544384u
#define OFF_H0R   23068672u                   // bf16 ring[256][64][1024]  (32 MB)
#define OFF_H1R   56623104u                   // bf16 ring[8][64][1024]    (1 MB)
#define OFF_H1ALL 57671680u                   // bf16 h1_all[512*64][1024] (64 MB)
#define OFF_SYNC  124780544u                  // real flags
#define SYNC_BYTES 16640u
#define OFF_SYNC2 (OFF_SYNC + SYNC_BYTES)     // scratch flags (V_nostore)
#define OFF_SYNC3 (OFF_SYNC2 + SYNC_BYTES)    // scratch flags (V_noload)
#define WS_TOTAL  (OFF_SYNC3 + SYNC_BYTES)

static __device__ __forceinline__ u16 f2b(float f) {
  uint32_t u = __float_as_uint(f);
  u += 0x7FFFu + ((u >> 16) & 1u);
  return (u16)(u >> 16);
}
static __device__ __forceinline__ float sigm(float x) { return 1.0f / (1.0f + __expf(-x)); }

__global__ void cvt_kernel(const float* __restrict__ src, u16* __restrict__ dst, int n) {
  int i = ((int)blockIdx.x * 256 + (int)threadIdx.x) * 4;
  if (i + 4 <= n) {
    const float4 v = *(const float4*)(src + i);
    ushort4 o;
    o.x = f2b(v.x); o.y = f2b(v.y); o.z = f2b(v.z); o.w = f2b(v.w);
    *(ushort4*)(dst + i) = o;
  }
}

__global__ void xt_kernel(const int* __restrict__ x, int* __restrict__ xT) {
  const int t = (int)blockIdx.x, b = (int)threadIdx.x;
  xT[t * BATCH + b] = x[b * T_LEN + t];
}

// -------- persistent RNN (R13 structure), MODE: 0=real 1=nosync 2=nostore 3=noload --------
template <int MODE>
__global__ __launch_bounds__(RNN_THREADS, 1) void rnn_k(
    const int* __restrict__ xT, const u16* __restrict__ embtab,
    const u16* __restrict__ A0i_r, const u16* __restrict__ A0i_z, const u16* __restrict__ A0i_n,
    const u16* __restrict__ A0h_r, const u16* __restrict__ A0h_z, const u16* __restrict__ A0h_n,
    const u16* __restrict__ A1i_r, const u16* __restrict__ A1i_z, const u16* __restrict__ A1i_n,
    const u16* __restrict__ A1h_r, const u16* __restrict__ A1h_z, const u16* __restrict__ A1h_n,
    const float* __restrict__ bih0, const float* __restrict__ bhh0,
    const float* __restrict__ bih1, const float* __restrict__ bhh1,
    u16* __restrict__ h0r, u16* __restrict__ h1r,
    u16* __restrict__ h1all, unsigned* __restrict__ sync)
{
  __shared__ __align__(16) float lds[16384];
  const int tid = (int)threadIdx.x;
  const int wv = tid >> 6;
  const int lane = tid & 63;
  const int lrow = lane & 15;
  const int lk8 = (lane >> 4) << 3;
  const int wgid = (int)blockIdx.x;
  const int layer = wgid >> 6;
  const int ubase = (wgid & 63) << 4;
  const bool iwave = (wv < 4);
  const bool l0i = (layer == 0) && iwave;
  unsigned* p0 = sync;
  unsigned* p1 = sync + 64 * 32;

  const u16 *Ar, *Az, *An;
  int ldb, k0;
  if (layer == 0) {
    if (iwave) { Ar = A0i_r; Az = A0i_z; An = A0i_n; ldb = EMB_D; k0 = wv * 128; }
    else       { Ar = A0h_r; Az = A0h_z; An = A0h_n; ldb = HID;   k0 = (wv - 4) * 256; }
  } else {
    if (iwave) { Ar = A1i_r; Az = A1i_z; An = A1i_n; ldb = HID;   k0 = wv * 256; }
    else       { Ar = A1h_r; Az = A1h_z; An = A1h_n; ldb = HID;   k0 = (wv - 4) * 256; }
  }
  const size_t arow = (size_t)(ubase + lrow) * ldb;

  const float* bi = layer ? bih1 : bih0;
  const float* bh = layer ? bhh1 : bhh0;
  const int u0 = (tid & 7) * 2;
  const int eb = tid >> 3;
  const int eug0 = ubase + u0, eug1 = eug0 + 1;
  const float bR0 = bi[eug0] + bh[eug0];
  const float bZ0 = bi[HID + eug0] + bh[HID + eug0];
  const float bNi0 = bi[2 * HID + eug0];
  const float bNh0 = bh[2 * HID + eug0];
  const float bR1 = bi[eug1] + bh[eug1];
  const float bZ1 = bi[HID + eug1] + bh[HID + eug1];
  const float bNi1 = bi[2 * HID + eug1];
  const float bNh1 = bh[2 * HID + eug1];
  const int l_e = ((u0 >> 2) << 4) | (eb & 15);
  const int r0 = u0 & 3, r1 = r0 + 1;
  const int ebt = eb >> 4;
  const int ix0 = l_e ^ (r0 << 3), ix1 = l_e ^ (r1 << 3);
  float hp0 = 0.f, hp1 = 0.f;

  const int sBeg = (layer == 0) ? 0 : 1;
  const int sEnd = (layer == 0) ? (T_LEN - 1) : T_LEN;

  for (int s = sBeg; s <= sEnd; ++s) {
    // ---- dependency poll ----
    if (MODE != 1) {
      unsigned t0, t1;
      if (layer == 0) { t0 = (unsigned)s; t1 = (s >= 252) ? (unsigned)(s - 250) : 0u; }
      else            { t0 = (unsigned)s; t1 = (unsigned)(s - 1); }
      if (tid < 128) {
        unsigned* f = (tid < 64) ? (p0 + (size_t)tid * 32) : (p1 + (size_t)(tid - 64) * 32);
        const unsigned tgt = (tid < 64) ? t0 : t1;
        while (__hip_atomic_load(f, __ATOMIC_RELAXED, __HIP_MEMORY_SCOPE_AGENT) < tgt)
          __builtin_amdgcn_s_sleep(1);
      }
    }
    __syncthreads();

    {
      const u16* h0prev = h0r + (size_t)((s - 1) & (R0 - 1)) * SLOT;
      const u16* h1prev = h1r + (size_t)((s - 2) & (R1 - 1)) * SLOT;

      f32x4 acc0[4], acc1[4], accn[4];
#pragma unroll
      for (int bt = 0; bt < 4; ++bt) {
        acc0[bt] = (f32x4){0.f, 0.f, 0.f, 0.f};
        acc1[bt] = (f32x4){0.f, 0.f, 0.f, 0.f};
        accn[bt] = (f32x4){0.f, 0.f, 0.f, 0.f};
      }
      if (l0i) {
        const u16* brow[4];
#pragma unroll
        for (int bt = 0; bt < 4; ++bt) {
          const int tok = (MODE == 3) ? 0 : xT[s * BATCH + bt * 16 + lrow];
          brow[bt] = embtab + (size_t)tok * EMB_D;
        }
#pragma unroll
        for (int ks = 0; ks < 4; ++ks) {
          const int kk = k0 + ks * 32 + lk8;
          const short8 ar = *(const short8*)(Ar + arow + kk);
          const short8 az = *(const short8*)(Az + arow + kk);
          const short8 an = *(const short8*)(An + arow + kk);
          short8 b0, b1, b2, b3;
          if (MODE == 3) {
            b0 = b1 = b2 = b3 = (short8)(short)0x3F80;
          } else {
            b0 = *(const short8*)(brow[0] + kk);
            b1 = *(const short8*)(brow[1] + kk);
            b2 = *(const short8*)(brow[2] + kk);
            b3 = *(const short8*)(brow[3] + kk);
          }
          acc0[0] = MFMA16(ar, b0, acc0[0]); acc1[0] = MFMA16(az, b0, acc1[0]); accn[0] = MFMA16(an, b0, accn[0]);
          acc0[1] = MFMA16(ar, b1, acc0[1]); acc1[1] = MFMA16(az, b1, acc1[1]); accn[1] = MFMA16(an, b1, accn[1]);
          acc0[2] = MFMA16(ar, b2, acc0[2]); acc1[2] = MFMA16(az, b2, acc1[2]); accn[2] = MFMA16(an, b2, accn[2]);
          acc0[3] = MFMA16(ar, b3, acc0[3]); acc1[3] = MFMA16(az, b3, acc1[3]); accn[3] = MFMA16(an, b3, accn[3]);
        }
      } else {
        const u16* Bp;
        if (layer == 0) Bp = h0prev;
        else            Bp = iwave ? h0prev : h1prev;
#pragma unroll
        for (int ks = 0; ks < 8; ++ks) {
          const int kk = k0 + ks * 32 + lk8;
          const short8 ar = *(const short8*)(Ar + arow + kk);
          const short8 az = *(const short8*)(Az + arow + kk);
          const short8 an = *(const short8*)(An + arow + kk);
#pragma unroll
          for (int bt = 0; bt < 4; ++bt) {
            short8 bf;
            if (MODE == 3) bf = (short8)(short)0x3F80;
            else           bf = *(const short8*)(Bp + (size_t)(bt * 16 + lrow) * HID + kk);
            acc0[bt] = MFMA16(ar, bf, acc0[bt]);
            acc1[bt] = MFMA16(az, bf, acc1[bt]);
            accn[bt] = MFMA16(an, bf, accn[bt]);
          }
        }
      }
      if (iwave) {
#pragma unroll
        for (int bt = 0; bt < 4; ++bt)
#pragma unroll
          for (int r = 0; r < 4; ++r) {
            const int ix = lane ^ (r << 3);
            lds[(((wv * 4 + 0) * 4 + bt) * 256) + r * 64 + ix] = acc0[bt][r];
            lds[(((wv * 4 + 1) * 4 + bt) * 256) + r * 64 + ix] = acc1[bt][r];
            lds[(((wv * 4 + 2) * 4 + bt) * 256) + r * 64 + ix] = accn[bt][r];
          }
      }
      __syncthreads();
      if (!iwave) {
        const int z = wv - 4;
#pragma unroll
        for (int bt = 0; bt < 4; ++bt)
#pragma unroll
          for (int r = 0; r < 4; ++r) {
            const int ix = lane ^ (r << 3);
            float* q0 = &lds[(((z * 4 + 0) * 4 + bt) * 256) + r * 64 + ix];
            float* q1 = &lds[(((z * 4 + 1) * 4 + bt) * 256) + r * 64 + ix];
            *q0 = *q0 + acc0[bt][r];
            *q1 = *q1 + acc1[bt][r];
            lds[(((z * 4 + 3) * 4 + bt) * 256) + r * 64 + ix] = accn[bt][r];
          }
      }
      __syncthreads();
      {
        float sr0 = 0.f, sz0 = 0.f, sni0 = 0.f, snh0 = 0.f;
        float sr1 = 0.f, sz1 = 0.f, sni1 = 0.f, snh1 = 0.f;
#pragma unroll
        for (int z = 0; z < 4; ++z) {
          sr0  += lds[(((z * 4 + 0) * 4 + ebt) * 256) + r0 * 64 + ix0];
          sz0  += lds[(((z * 4 + 1) * 4 + ebt) * 256) + r0 * 64 + ix0];
          sni0 += lds[(((z * 4 + 2) * 4 + ebt) * 256) + r0 * 64 + ix0];
          snh0 += lds[(((z * 4 + 3) * 4 + ebt) * 256) + r0 * 64 + ix0];
          sr1  += lds[(((z * 4 + 0) * 4 + ebt) * 256) + r1 * 64 + ix1];
          sz1  += lds[(((z * 4 + 1) * 4 + ebt) * 256) + r1 * 64 + ix1];
          sni1 += lds[(((z * 4 + 2) * 4 + ebt) * 256) + r1 * 64 + ix1];
          sni1 += 0.f;
          snh1 += lds[(((z * 4 + 3) * 4 + ebt) * 256) + r1 * 64 + ix1];
        }
        const float rg0 = sigm(sr0 + bR0);
        const float zg0 = sigm(sz0 + bZ0);
        const float ng0 = tanhf(sni0 + bNi0 + rg0 * (snh0 + bNh0));
        const float hn0 = (1.0f - zg0) * ng0 + zg0 * hp0;
        const float rg1 = sigm(sr1 + bR1);
        const float zg1 = sigm(sz1 + bZ1);
        const float ng1 = tanhf(sni1 + bNi1 + rg1 * (snh1 + bNh1));
        const float hn1 = (1.0f - zg1) * ng1 + zg1 * hp1;
        hp0 = hn0; hp1 = hn1;
        const unsigned packed = (unsigned)f2b(hn0) | ((unsigned)f2b(hn1) << 16);
        if (MODE != 2) {
          u16* wslot = layer ? (h1r + (size_t)((s - 1) & (R1 - 1)) * SLOT)
                             : (h0r + (size_t)(s & (R0 - 1)) * SLOT);
          __hip_atomic_store((unsigned*)&wslot[eb * HID + eug0], packed,
                             __ATOMIC_RELAXED, __HIP_MEMORY_SCOPE_AGENT);
          if (layer)
            *(unsigned*)&h1all[((size_t)(s - 1) * BATCH + eb) * HID + eug0] = packed;
        } else {
          SINK(packed);
        }
      }
    }
    __syncthreads();
    if (MODE != 1) {
      if (tid == 0) {
        unsigned* f = layer ? (p1 + (size_t)(wgid - 64) * 32) : (p0 + (size_t)wgid * 32);
        __hip_atomic_store(f, (unsigned)(s + (layer ? 0 : 1)), __ATOMIC_RELAXED,
                           __HIP_MEMORY_SCOPE_AGENT);
      }
    }
  }
}

// -------- epilogue logits (R5-verified MFMA path, decode-0) --------
__global__ __launch_bounds__(256, 2) void logits_kernel(
    const u16* __restrict__ h1all, const u16* __restrict__ Woutb,
    const float* __restrict__ bout, float* __restrict__ out)
{
  __shared__ __align__(16) short lds[16 * 4 * 64 * 8];
  const int tid = (int)threadIdx.x;
  const int wv = tid >> 6, lane = tid & 63;
  const int lrow = lane & 15, lk8 = (lane >> 4) << 3;
  const int row0 = (int)blockIdx.x * 64 + wv * 16;
  f32x4 acc[16];
#pragma unroll
  for (int i = 0; i < 16; ++i) acc[i] = (f32x4){0.f, 0.f, 0.f, 0.f};

  for (int kc = 0; kc < HID; kc += 128) {
    __syncthreads();
#pragma unroll
    for (int j = 0; j < 16; ++j) {
      const int slot = tid + j * 256;
      const int ct = slot >> 8, kt = (slot >> 6) & 3, l = slot & 63;
      *(short8*)&lds[slot * 8] =
          *(const short8*)(Woutb + (size_t)(ct * 16 + (l & 15)) * HID + kc + kt * 32 + ((l >> 4) << 3));
    }
    __syncthreads();
#pragma unroll
    for (int kt = 0; kt < 4; ++kt) {
      const short8 af = *(const short8*)(h1all + (size_t)(row0 + lrow) * HID + kc + kt * 32 + lk8);
#pragma unroll
      for (int ct = 0; ct < 16; ++ct) {
        const short8 bf = *(const short8*)&lds[((ct * 4 + kt) * 64 + lane) * 8];
        acc[ct] = MFMA16(af, bf, acc[ct]);
      }
    }
  }
#pragma unroll
  for (int ct = 0; ct < 16; ++ct) {
    const int v = ct * 16 + lrow;
    const float bo = bout[v];
#pragma unroll
    for (int r = 0; r < 4; ++r) {
      const int row = row0 + (lane >> 4) * 4 + r;
      const int t = row >> 6, b = row & 63;
      out[((size_t)(b * T_LEN + t)) * VOC + v] = acc[ct][r] + bo;
    }
  }
}

extern "C" void kernel_launch(void* const* d_in, const int* in_sizes, int n_in,
                              void* d_out, int out_size, void* d_ws, size_t ws_size,
                              hipStream_t stream) {
  const int*   x     = (const int*)d_in[0];
  const float* embed = (const float*)d_in[1];
  const float* Wih0  = (const float*)d_in[2];
  const float* Whh0  = (const float*)d_in[3];
  const float* bih0  = (const float*)d_in[4];
  const float* bhh0  = (const float*)d_in[5];
  const float* Wih1  = (const float*)d_in[6];
  const float* Whh1  = (const float*)d_in[7];
  const float* bih1  = (const float*)d_in[8];
  const float* bhh1  = (const float*)d_in[9];
  const float* Wout  = (const float*)d_in[10];
  const float* bout  = (const float*)d_in[11];
  float* out = (float*)d_out;
  char* ws = (char*)d_ws;
  if (ws_size < (size_t)WS_TOTAL) return;

  hipMemsetAsync(ws + OFF_H0R + (size_t)(R0 - 1) * SLOT * 2, 0, SLOT * 2, stream);
  hipMemsetAsync(ws + OFF_H1R + (size_t)(R1 - 1) * SLOT * 2, 0, SLOT * 2, stream);
  hipMemsetAsync(ws + OFF_SYNC, 0, 3 * SYNC_BYTES, stream);
  xt_kernel<<<512, 64, 0, stream>>>(x, (int*)(ws + OFF_XT));
  cvt_kernel<<<128, 256, 0, stream>>>(embed, (u16*)(ws + OFF_EMBT), 256 * 512);
  cvt_kernel<<<1536, 256, 0, stream>>>(Wih0, (u16*)(ws + OFF_WIH0), 3072 * 512);
  cvt_kernel<<<3072, 256, 0, stream>>>(Whh0, (u16*)(ws + OFF_WHH0), 3072 * 1024);
  cvt_kernel<<<3072, 256, 0, stream>>>(Wih1, (u16*)(ws + OFF_WIH1), 3072 * 1024);
  cvt_kernel<<<3072, 256, 0, stream>>>(Whh1, (u16*)(ws + OFF_WHH1), 3072 * 1024);
  cvt_kernel<<<256, 256, 0, stream>>>(Wout, (u16*)(ws + OFF_WOUT), 256 * 1024);

  const u16* wih0b = (const u16*)(ws + OFF_WIH0);
  const u16* whh0b = (const u16*)(ws + OFF_WHH0);
  const u16* wih1b = (const u16*)(ws + OFF_WIH1);
  const u16* whh1b = (const u16*)(ws + OFF_WHH1);

#define RNN_ARGS(SYNCOFF)                                                        \
      (const int*)(ws + OFF_XT), (const u16*)(ws + OFF_EMBT),                    \
      wih0b, wih0b + 524288, wih0b + 1048576,                                    \
      whh0b, whh0b + 1048576, whh0b + 2097152,                                   \
      wih1b, wih1b + 1048576, wih1b + 2097152,                                   \
      whh1b, whh1b + 1048576, whh1b + 2097152,                                   \
      bih0, bhh0, bih1, bhh1,                                                    \
      (u16*)(ws + OFF_H0R), (u16*)(ws + OFF_H1R),                                \
      (u16*)(ws + OFF_H1ALL), (unsigned*)(ws + (SYNCOFF))

  // real pipeline (R13-identical)
  rnn_k<0><<<NWG, RNN_THREADS, 0, stream>>>(RNN_ARGS(OFF_SYNC));
  logits_kernel<<<512, 256, 0, stream>>>((const u16*)(ws + OFF_H1ALL),
                                         (const u16*)(ws + OFF_WOUT), bout, out);

  // diagnostic scratch variants (clobber dead rings/h1all; never touch out)
  rnn_k<1><<<NWG, RNN_THREADS, 0, stream>>>(RNN_ARGS(OFF_SYNC));   // nosync (flags unused)
  rnn_k<2><<<NWG, RNN_THREADS, 0, stream>>>(RNN_ARGS(OFF_SYNC2));  // nostore
  rnn_k<3><<<NWG, RNN_THREADS, 0, stream>>>(RNN_ARGS(OFF_SYNC3));  // noload
#undef RNN_ARGS
}

// Round 16
// 9401.314 us; speedup vs baseline: 2.8656x; 2.8656x over previous
//
#include <hip/hip_runtime.h>
#include <stdint.h>

typedef short short8 __attribute__((ext_vector_type(8)));
typedef float f32x4 __attribute__((ext_vector_type(4)));
typedef unsigned short u16;
typedef unsigned long long u64;

#define MFMA16(a, b, c) __builtin_amdgcn_mfma_f32_16x16x32_bf16((a), (b), (c), 0, 0, 0)

#define T_LEN 512
#define BATCH 64
#define EMB_D 512
#define HID 1024
#define VOC 256
#define NWG 256
#define THREADS 128
#define R0 256                                // h0 ring slots
#define R1 8                                  // h1 ring slots
#define SLOT (BATCH * HID)                    // u16 elems per ring slot (65536)

// -------- workspace layout (bytes) --------
#define OFF_XT    0u                          // int xT[512][64]
#define OFF_EMBT  131072u                     // bf16 embtab[256][512]
#define OFF_WIH0  524288u                     // bf16 [3072][512]
#define OFF_WHH0  3670016u                    // bf16 [3072][1024]
#define OFF_WIH1  9961472u
#define OFF_WHH1  16252928u
#define OFF_WOUT  22544384u                   // bf16 [256][1024]
#define OFF_H0R   23068672u                   // bf16 ring[256][64][1024]  (32 MB)
#define OFF_H1R   56623104u                   // bf16 ring[8][64][1024]    (1 MB)
#define OFF_H1ALL 57671680u                   // bf16 h1_all[512*64][1024] (64 MB)
#define OFF_SYNC  124780544u                  // p0[4][64] + p1[4][64] wave-flag lines (128B apart)
#define SYNC_BYTES 65536u
#define WS_TOTAL  (OFF_SYNC + SYNC_BYTES)

static __device__ __forceinline__ u16 f2b(float f) {
  uint32_t u = __float_as_uint(f);
  u += 0x7FFFu + ((u >> 16) & 1u);   // round-to-nearest-even
  return (u16)(u >> 16);
}
static __device__ __forceinline__ float sigm(float x) { return 1.0f / (1.0f + __expf(-x)); }

// -------- f32 -> bf16 convert --------
__global__ void cvt_kernel(const float* __restrict__ src, u16* __restrict__ dst, int n) {
  int i = ((int)blockIdx.x * 256 + (int)threadIdx.x) * 4;
  if (i + 4 <= n) {
    const float4 v = *(const float4*)(src + i);
    ushort4 o;
    o.x = f2b(v.x); o.y = f2b(v.y); o.z = f2b(v.z); o.w = f2b(v.w);
    *(ushort4*)(dst + i) = o;
  }
}

// -------- token transpose: xT[t][b] = x[b][t] --------
__global__ void xt_kernel(const int* __restrict__ x, int* __restrict__ xT) {
  const int t = (int)blockIdx.x, b = (int)threadIdx.x;
  xT[t * BATCH + b] = x[b * T_LEN + t];
}

// -------- persistent RNN: one wave = one 16x16 output tile, full K, no LDS --------
// 256 WGs x 128 threads. blockIdx = bb*64 + g, g = layer*32 + ub.
// blockIdx%8 == g%8  ->  all 4 batch-copies of a weight slice pin to one XCD
// (2.7 MB/XCD, L2-resident).  Sync: per-wave flags, lane-parallel domain polls.
__global__ __launch_bounds__(THREADS, 1) void rnn_persist_kernel(
    const int* __restrict__ xT, const u16* __restrict__ embtab,
    const u16* __restrict__ A0i_r, const u16* __restrict__ A0i_z, const u16* __restrict__ A0i_n,
    const u16* __restrict__ A0h_r, const u16* __restrict__ A0h_z, const u16* __restrict__ A0h_n,
    const u16* __restrict__ A1i_r, const u16* __restrict__ A1i_z, const u16* __restrict__ A1i_n,
    const u16* __restrict__ A1h_r, const u16* __restrict__ A1h_z, const u16* __restrict__ A1h_n,
    const float* __restrict__ bih0, const float* __restrict__ bhh0,
    const float* __restrict__ bih1, const float* __restrict__ bhh1,
    u16* __restrict__ h0r, u16* __restrict__ h1r,
    u16* __restrict__ h1all, unsigned* __restrict__ sync)
{
  const int tid = (int)threadIdx.x;
  const int wv = tid >> 6;                 // 0..1
  const int lane = tid & 63;
  const int lrow = lane & 15;
  const int lk8 = (lane >> 4) << 3;
  const int bb = (int)blockIdx.x >> 6;     // batch-block 0..3
  const int g = (int)blockIdx.x & 63;      // weight-group (XCD-pinned)
  const int layer = g >> 5;
  const int ub = g & 31;                   // unit-block (32 units)

  unsigned* p0 = sync;                     // [bb*64 + widx]*32
  unsigned* p1 = sync + 4 * 64 * 32;
  const int widx = ub * 2 + wv;            // 0..63 within (layer,bb) domain
  unsigned* myflag = (layer ? p1 : p0) + (size_t)(bb * 64 + widx) * 32;
  unsigned* pollf0 = p0 + (size_t)(bb * 64 + lane) * 32;  // lane-parallel
  unsigned* pollf1 = p1 + (size_t)(bb * 64 + lane) * 32;

  // ---- per-gate weight bases (R6-safe: separate args, no big const offsets) ----
  const u16 *Axr, *Axz, *Axn, *Ahr, *Ahz, *Ahn;
  int ldx;
  if (layer == 0) { Axr = A0i_r; Axz = A0i_z; Axn = A0i_n;
                    Ahr = A0h_r; Ahz = A0h_z; Ahn = A0h_n; ldx = EMB_D; }
  else            { Axr = A1i_r; Axz = A1i_z; Axn = A1i_n;
                    Ahr = A1h_r; Ahz = A1h_z; Ahn = A1h_n; ldx = HID; }
  const int urow = ub * 32 + wv * 16 + lrow;       // weight row (unit)
  const size_t axrow = (size_t)urow * ldx;
  const size_t ahrow = (size_t)urow * HID;
  const int brow = bb * 16 + lrow;                 // activation row (batch)

  // ---- per-lane epilogue constants: 4 units (consecutive), 1 batch ----
  const float* bi = layer ? bih1 : bih0;
  const float* bh = layer ? bhh1 : bhh0;
  const int ubase_l = ub * 32 + wv * 16 + (lane >> 4) * 4;
  const int batch = bb * 16 + (lane & 15);
  float bR[4], bZ[4], bNi[4], bNh[4], hp[4];
#pragma unroll
  for (int r = 0; r < 4; ++r) {
    const int ug = ubase_l + r;
    bR[r] = bi[ug] + bh[ug];
    bZ[r] = bi[HID + ug] + bh[HID + ug];
    bNi[r] = bi[2 * HID + ug];
    bNh[r] = bh[2 * HID + ug];
    hp[r] = 0.f;
  }
  const size_t hoff = (size_t)batch * HID + ubase_l;   // 8B-aligned (ubase_l%4==0)

  const int sBeg = layer ? 1 : 0;
  const int sEnd = layer ? T_LEN : (T_LEN - 1);

  for (int s = sBeg; s <= sEnd; ++s) {
    // ---- dependency polls (lane-parallel over the 64 domain producer-waves) ----
    {
      const unsigned t0 = (unsigned)s;     // need h0(s-1): p0 flag = completed h0 count
      unsigned v = __hip_atomic_load(pollf0, __ATOMIC_RELAXED, __HIP_MEMORY_SCOPE_AGENT);
      while (v < t0) { __builtin_amdgcn_s_sleep(1);
        v = __hip_atomic_load(pollf0, __ATOMIC_RELAXED, __HIP_MEMORY_SCOPE_AGENT); }
    }
    if (layer) {                            // need h1(s-2): p1 >= s-1
      const unsigned t1 = (unsigned)(s - 1);
      unsigned v = __hip_atomic_load(pollf1, __ATOMIC_RELAXED, __HIP_MEMORY_SCOPE_AGENT);
      while (v < t1) { __builtin_amdgcn_s_sleep(1);
        v = __hip_atomic_load(pollf1, __ATOMIC_RELAXED, __HIP_MEMORY_SCOPE_AGENT); }
    } else if (s >= 252) {                  // h0-ring back-pressure (R0=256, margin 5)
      const unsigned t1 = (unsigned)(s - 250);
      unsigned v = __hip_atomic_load(pollf1, __ATOMIC_RELAXED, __HIP_MEMORY_SCOPE_AGENT);
      while (v < t1) { __builtin_amdgcn_s_sleep(1);
        v = __hip_atomic_load(pollf1, __ATOMIC_RELAXED, __HIP_MEMORY_SCOPE_AGENT); }
    }

    const u16* h0p = h0r + (size_t)((s - 1) & (R0 - 1)) * SLOT;
    const u16* h1p = h1r + (size_t)((s - 2) & (R1 - 1)) * SLOT;

    f32x4 aR = {0.f, 0.f, 0.f, 0.f}, aZ = aR, aNi = aR, aNh = aR;

    // ---- x-part: r,z,ni (unconditional MFMAs) ----
    if (layer == 0) {
      const int tok = xT[s * BATCH + brow];
      const u16* Bx = embtab + (size_t)tok * EMB_D;
#pragma unroll 8
      for (int ks = 0; ks < 16; ++ks) {
        const int kk = ks * 32 + lk8;
        const short8 ar = *(const short8*)(Axr + axrow + kk);
        const short8 az = *(const short8*)(Axz + axrow + kk);
        const short8 an = *(const short8*)(Axn + axrow + kk);
        const short8 bf = *(const short8*)(Bx + kk);
        aR = MFMA16(ar, bf, aR);
        aZ = MFMA16(az, bf, aZ);
        aNi = MFMA16(an, bf, aNi);
      }
    } else {
      const u16* Bx = h0p + (size_t)brow * HID;
#pragma unroll 8
      for (int ks = 0; ks < 32; ++ks) {
        const int kk = ks * 32 + lk8;
        const short8 ar = *(const short8*)(Axr + axrow + kk);
        const short8 az = *(const short8*)(Axz + axrow + kk);
        const short8 an = *(const short8*)(Axn + axrow + kk);
        const short8 bf = *(const short8*)(Bx + kk);
        aR = MFMA16(ar, bf, aR);
        aZ = MFMA16(az, bf, aZ);
        aNi = MFMA16(an, bf, aNi);
      }
    }
    // ---- h-part: r,z,nh ----
    {
      const u16* Bh = (layer ? h1p : h0p) + (size_t)brow * HID;
#pragma unroll 8
      for (int ks = 0; ks < 32; ++ks) {
        const int kk = ks * 32 + lk8;
        const short8 ar = *(const short8*)(Ahr + ahrow + kk);
        const short8 az = *(const short8*)(Ahz + ahrow + kk);
        const short8 an = *(const short8*)(Ahn + ahrow + kk);
        const short8 bf = *(const short8*)(Bh + kk);
        aR = MFMA16(ar, bf, aR);
        aZ = MFMA16(az, bf, aZ);
        aNh = MFMA16(an, bf, aNh);
      }
    }
    // ---- epilogue: 4 units per lane, packed 8B coherent store ----
    u16 hv0, hv1, hv2, hv3;
#pragma unroll
    for (int r = 0; r < 4; ++r) {
      const float rg = sigm(aR[r] + bR[r]);
      const float zg = sigm(aZ[r] + bZ[r]);
      const float ng = tanhf(aNi[r] + bNi[r] + rg * (aNh[r] + bNh[r]));
      const float hn = (1.0f - zg) * ng + zg * hp[r];
      hp[r] = hn;
      const u16 hv = f2b(hn);
      if (r == 0) hv0 = hv; else if (r == 1) hv1 = hv;
      else if (r == 2) hv2 = hv; else hv3 = hv;
    }
    const u64 packed = (u64)hv0 | ((u64)hv1 << 16) | ((u64)hv2 << 32) | ((u64)hv3 << 48);
    u16* wslot = layer ? (h1r + (size_t)((s - 1) & (R1 - 1)) * SLOT)
                       : (h0r + (size_t)(s & (R0 - 1)) * SLOT);
    __hip_atomic_store((u64*)(wslot + hoff), packed,
                       __ATOMIC_RELAXED, __HIP_MEMORY_SCOPE_AGENT);
    if (layer)
      *(u64*)(h1all + ((size_t)(s - 1) * BATCH + batch) * HID + ubase_l) = packed;

    // ---- publish: drain this wave's stores, then flag (per-wave, lane 0) ----
    asm volatile("s_waitcnt vmcnt(0)" ::: "memory");
    if (lane == 0)
      __hip_atomic_store(myflag, (unsigned)(layer ? s : s + 1),
                         __ATOMIC_RELAXED, __HIP_MEMORY_SCOPE_AGENT);
  }
}

// -------- epilogue logits (R5-verified MFMA path, decode-0) --------
__global__ __launch_bounds__(256, 2) void logits_kernel(
    const u16* __restrict__ h1all, const u16* __restrict__ Woutb,
    const float* __restrict__ bout, float* __restrict__ out)
{
  __shared__ __align__(16) short lds[16 * 4 * 64 * 8];
  const int tid = (int)threadIdx.x;
  const int wv = tid >> 6, lane = tid & 63;
  const int lrow = lane & 15, lk8 = (lane >> 4) << 3;
  const int row0 = (int)blockIdx.x * 64 + wv * 16;
  f32x4 acc[16];
#pragma unroll
  for (int i = 0; i < 16; ++i) acc[i] = (f32x4){0.f, 0.f, 0.f, 0.f};

  for (int kc = 0; kc < HID; kc += 128) {
    __syncthreads();
#pragma unroll
    for (int j = 0; j < 16; ++j) {
      const int slot = tid + j * 256;
      const int ct = slot >> 8, kt = (slot >> 6) & 3, l = slot & 63;
      *(short8*)&lds[slot * 8] =
          *(const short8*)(Woutb + (size_t)(ct * 16 + (l & 15)) * HID + kc + kt * 32 + ((l >> 4) << 3));
    }
    __syncthreads();
#pragma unroll
    for (int kt = 0; kt < 4; ++kt) {
      const short8 af = *(const short8*)(h1all + (size_t)(row0 + lrow) * HID + kc + kt * 32 + lk8);
#pragma unroll
      for (int ct = 0; ct < 16; ++ct) {
        const short8 bf = *(const short8*)&lds[((ct * 4 + kt) * 64 + lane) * 8];
        acc[ct] = MFMA16(af, bf, acc[ct]);
      }
    }
  }
#pragma unroll
  for (int ct = 0; ct < 16; ++ct) {
    const int v = ct * 16 + lrow;
    const float bo = bout[v];
#pragma unroll
    for (int r = 0; r < 4; ++r) {
      const int row = row0 + (lane >> 4) * 4 + r;  // row = t*64 + b
      const int t = row >> 6, b = row & 63;
      out[((size_t)(b * T_LEN + t)) * VOC + v] = acc[ct][r] + bo;
    }
  }
}

extern "C" void kernel_launch(void* const* d_in, const int* in_sizes, int n_in,
                              void* d_out, int out_size, void* d_ws, size_t ws_size,
                              hipStream_t stream) {
  const int*   x     = (const int*)d_in[0];
  const float* embed = (const float*)d_in[1];
  const float* Wih0  = (const float*)d_in[2];
  const float* Whh0  = (const float*)d_in[3];
  const float* bih0  = (const float*)d_in[4];
  const float* bhh0  = (const float*)d_in[5];
  const float* Wih1  = (const float*)d_in[6];
  const float* Whh1  = (const float*)d_in[7];
  const float* bih1  = (const float*)d_in[8];
  const float* bhh1  = (const float*)d_in[9];
  const float* Wout  = (const float*)d_in[10];
  const float* bout  = (const float*)d_in[11];
  float* out = (float*)d_out;
  char* ws = (char*)d_ws;
  if (ws_size < (size_t)WS_TOTAL) return;

  // zero: h0 ring slot 255 (h0(-1)=0), h1 ring slot 7 (h1(-1)=0), wave flags
  hipMemsetAsync(ws + OFF_H0R + (size_t)(R0 - 1) * SLOT * 2, 0, SLOT * 2, stream);
  hipMemsetAsync(ws + OFF_H1R + (size_t)(R1 - 1) * SLOT * 2, 0, SLOT * 2, stream);
  hipMemsetAsync(ws + OFF_SYNC, 0, SYNC_BYTES, stream);
  xt_kernel<<<512, 64, 0, stream>>>(x, (int*)(ws + OFF_XT));
  cvt_kernel<<<128, 256, 0, stream>>>(embed, (u16*)(ws + OFF_EMBT), 256 * 512);
  cvt_kernel<<<1536, 256, 0, stream>>>(Wih0, (u16*)(ws + OFF_WIH0), 3072 * 512);
  cvt_kernel<<<3072, 256, 0, stream>>>(Whh0, (u16*)(ws + OFF_WHH0), 3072 * 1024);
  cvt_kernel<<<3072, 256, 0, stream>>>(Wih1, (u16*)(ws + OFF_WIH1), 3072 * 1024);
  cvt_kernel<<<3072, 256, 0, stream>>>(Whh1, (u16*)(ws + OFF_WHH1), 3072 * 1024);
  cvt_kernel<<<256, 256, 0, stream>>>(Wout, (u16*)(ws + OFF_WOUT), 256 * 1024);

  const u16* wih0b = (const u16*)(ws + OFF_WIH0);
  const u16* whh0b = (const u16*)(ws + OFF_WHH0);
  const u16* wih1b = (const u16*)(ws + OFF_WIH1);
  const u16* whh1b = (const u16*)(ws + OFF_WHH1);

  rnn_persist_kernel<<<NWG, THREADS, 0, stream>>>(
      (const int*)(ws + OFF_XT), (const u16*)(ws + OFF_EMBT),
      wih0b, wih0b + 524288, wih0b + 1048576,
      whh0b, whh0b + 1048576, whh0b + 2097152,
      wih1b, wih1b + 1048576, wih1b + 2097152,
      whh1b, whh1b + 1048576, whh1b + 2097152,
      bih0, bhh0, bih1, bhh1,
      (u16*)(ws + OFF_H0R), (u16*)(ws + OFF_H1R),
      (u16*)(ws + OFF_H1ALL), (unsigned*)(ws + OFF_SYNC));

  logits_kernel<<<512, 256, 0, stream>>>((const u16*)(ws + OFF_H1ALL),
                                         (const u16*)(ws + OFF_WOUT), bout, out);
}

// Round 17
// 7804.732 us; speedup vs baseline: 3.4518x; 1.2046x over previous
//
#include <hip/hip_runtime.h>
#include <stdint.h>

typedef short short8 __attribute__((ext_vector_type(8)));
typedef float f32x4 __attribute__((ext_vector_type(4)));
typedef unsigned short u16;

#define MFMA16(a, b, c) __builtin_amdgcn_mfma_f32_16x16x32_bf16((a), (b), (c), 0, 0, 0)

#define T_LEN 512
#define BATCH 64
#define EMB_D 512
#define HID 1024
#define VOC 256
#define NWG 128
#define RNN_THREADS 512
#define R0 256                                // h0 ring slots
#define R1 8                                  // h1 ring slots
#define SLOT (BATCH * HID)                    // u16 elems per ring slot (65536)

// -------- workspace layout (bytes) --------
#define OFF_XT    0u                          // int xT[512][64]
#define OFF_EMBT  131072u                     // bf16 embtab[256][512]
#define OFF_WIH0  524288u                     // bf16 [3072][512]
#define OFF_WHH0  3670016u                    // bf16 [3072][1024]
#define OFF_WIH1  9961472u
#define OFF_WHH1  16252928u
#define OFF_WOUT  22544384u                   // bf16 [256][1024]
#define OFF_H0R   23068672u                   // bf16 ring[256][64][1024]  (32 MB)
#define OFF_H1R   56623104u                   // bf16 ring[8][64][1024]    (1 MB)
#define OFF_H1ALL 57671680u                   // bf16 h1_all[512*64][1024] (64 MB)
#define OFF_SYNC  124780544u                  // p0[64]+p1[64] flag lines, 128B apart
#define SYNC_BYTES 16640u
#define WS_TOTAL  (OFF_SYNC + SYNC_BYTES)

static __device__ __forceinline__ u16 f2b(float f) {
  uint32_t u = __float_as_uint(f);
  u += 0x7FFFu + ((u >> 16) & 1u);   // round-to-nearest-even
  return (u16)(u >> 16);
}
static __device__ __forceinline__ float sigm(float x) { return 1.0f / (1.0f + __expf(-x)); }

// -------- f32 -> bf16 convert --------
__global__ void cvt_kernel(const float* __restrict__ src, u16* __restrict__ dst, int n) {
  int i = ((int)blockIdx.x * 256 + (int)threadIdx.x) * 4;
  if (i + 4 <= n) {
    const float4 v = *(const float4*)(src + i);
    ushort4 o;
    o.x = f2b(v.x); o.y = f2b(v.y); o.z = f2b(v.z); o.w = f2b(v.w);
    *(ushort4*)(dst + i) = o;
  }
}

// -------- token transpose: xT[t][b] = x[b][t] --------
__global__ void xt_kernel(const int* __restrict__ x, int* __restrict__ xT) {
  const int t = (int)blockIdx.x, b = (int)threadIdx.x;
  xT[t * BATCH + b] = x[b * T_LEN + t];
}

// poll: lanes 0-63 wait p0[lane] >= t0; lanes 64-127 wait p1[lane-64] >= t1
static __device__ __forceinline__ void poll_flags(unsigned* p0, unsigned* p1,
                                                  unsigned t0, unsigned t1, int tid) {
  if (tid < 128) {
    unsigned* f = (tid < 64) ? (p0 + (size_t)tid * 32) : (p1 + (size_t)(tid - 64) * 32);
    const unsigned tgt = (tid < 64) ? t0 : t1;
    while (__hip_atomic_load(f, __ATOMIC_RELAXED, __HIP_MEMORY_SCOPE_AGENT) < tgt)
      __builtin_amdgcn_s_sleep(1);
  }
  __syncthreads();
}

// -------- persistent RNN, decoupled chains (R13 base) --------
// R17 changes: (1) B-fragments prefetched in ONE load volley into registers
// (one exposed miss latency instead of per-ks serial misses); (2) h1all
// streaming store moved AFTER the flag publish (off the drain critical path).
__global__ __launch_bounds__(RNN_THREADS, 1) void rnn_persist_kernel(
    const int* __restrict__ xT, const u16* __restrict__ embtab,
    const u16* __restrict__ A0i_r, const u16* __restrict__ A0i_z, const u16* __restrict__ A0i_n,
    const u16* __restrict__ A0h_r, const u16* __restrict__ A0h_z, const u16* __restrict__ A0h_n,
    const u16* __restrict__ A1i_r, const u16* __restrict__ A1i_z, const u16* __restrict__ A1i_n,
    const u16* __restrict__ A1h_r, const u16* __restrict__ A1h_z, const u16* __restrict__ A1h_n,
    const float* __restrict__ bih0, const float* __restrict__ bhh0,
    const float* __restrict__ bih1, const float* __restrict__ bhh1,
    u16* __restrict__ h0r, u16* __restrict__ h1r,
    u16* __restrict__ h1all, unsigned* __restrict__ sync)
{
  __shared__ __align__(16) float lds[16384];
  const int tid = (int)threadIdx.x;
  const int wv = tid >> 6;
  const int lane = tid & 63;
  const int lrow = lane & 15;
  const int lk8 = (lane >> 4) << 3;
  const int wgid = (int)blockIdx.x;
  const int layer = wgid >> 6;
  const int ubase = (wgid & 63) << 4;
  const bool iwave = (wv < 4);
  const bool l0i = (layer == 0) && iwave;
  unsigned* p0 = sync;
  unsigned* p1 = sync + 64 * 32;

  // ---- role-uniform A config (R7-validated per-gate pointers) ----
  const u16 *Ar, *Az, *An;
  int ldb, k0;
  if (layer == 0) {
    if (iwave) { Ar = A0i_r; Az = A0i_z; An = A0i_n; ldb = EMB_D; k0 = wv * 128; }
    else       { Ar = A0h_r; Az = A0h_z; An = A0h_n; ldb = HID;   k0 = (wv - 4) * 256; }
  } else {
    if (iwave) { Ar = A1i_r; Az = A1i_z; An = A1i_n; ldb = HID;   k0 = wv * 256; }
    else       { Ar = A1h_r; Az = A1h_z; An = A1h_n; ldb = HID;   k0 = (wv - 4) * 256; }
  }
  const size_t arow = (size_t)(ubase + lrow) * ldb;

  // ---- epilogue constants: thread owns unit-pair (u0,u0+1) x batch eb ----
  const float* bi = layer ? bih1 : bih0;
  const float* bh = layer ? bhh1 : bhh0;
  const int u0 = (tid & 7) * 2;
  const int eb = tid >> 3;
  const int eug0 = ubase + u0, eug1 = eug0 + 1;
  const float bR0 = bi[eug0] + bh[eug0];
  const float bZ0 = bi[HID + eug0] + bh[HID + eug0];
  const float bNi0 = bi[2 * HID + eug0];
  const float bNh0 = bh[2 * HID + eug0];
  const float bR1 = bi[eug1] + bh[eug1];
  const float bZ1 = bi[HID + eug1] + bh[HID + eug1];
  const float bNi1 = bi[2 * HID + eug1];
  const float bNh1 = bh[2 * HID + eug1];
  const int l_e = ((u0 >> 2) << 4) | (eb & 15);
  const int r0 = u0 & 3, r1 = r0 + 1;
  const int ebt = eb >> 4;
  const int ix0 = l_e ^ (r0 << 3), ix1 = l_e ^ (r1 << 3);
  float hp0 = 0.f, hp1 = 0.f;

  const int sBeg = (layer == 0) ? 0 : 1;
  const int sEnd = (layer == 0) ? (T_LEN - 1) : T_LEN;

  for (int s = sBeg; s <= sEnd; ++s) {
    // ---- dependency poll ----
    if (layer == 0) {
      const unsigned bp = (s >= 252) ? (unsigned)(s - 250) : 0u;  // h0-ring back-pressure
      poll_flags(p0, p1, (unsigned)s, bp, tid);
    } else {
      poll_flags(p0, p1, (unsigned)s, (unsigned)(s - 1), tid);
    }

    unsigned packed;
    {
      const u16* h0prev = h0r + (size_t)((s - 1) & (R0 - 1)) * SLOT;
      const u16* h1prev = h1r + (size_t)((s - 2) & (R1 - 1)) * SLOT;

      f32x4 acc0[4], acc1[4], accn[4];
#pragma unroll
      for (int bt = 0; bt < 4; ++bt) {
        acc0[bt] = (f32x4){0.f, 0.f, 0.f, 0.f};
        acc1[bt] = (f32x4){0.f, 0.f, 0.f, 0.f};
        accn[bt] = (f32x4){0.f, 0.f, 0.f, 0.f};
      }
      if (l0i) {  // B = embed rows gathered by token (embtab L2-resident)
        const u16* brow[4];
#pragma unroll
        for (int bt = 0; bt < 4; ++bt) {
          const int tok = xT[s * BATCH + bt * 16 + lrow];
          brow[bt] = embtab + (size_t)tok * EMB_D;
        }
        // prefetch volley: all 16 B-fragments, static indices -> registers
        short8 bfr[4][4];
#pragma unroll
        for (int ks = 0; ks < 4; ++ks)
#pragma unroll
          for (int bt = 0; bt < 4; ++bt)
            bfr[bt][ks] = *(const short8*)(brow[bt] + k0 + ks * 32 + lk8);
#pragma unroll
        for (int ks = 0; ks < 4; ++ks) {
          const int kk = k0 + ks * 32 + lk8;
          const short8 ar = *(const short8*)(Ar + arow + kk);
          const short8 az = *(const short8*)(Az + arow + kk);
          const short8 an = *(const short8*)(An + arow + kk);
#pragma unroll
          for (int bt = 0; bt < 4; ++bt) {
            acc0[bt] = MFMA16(ar, bfr[bt][ks], acc0[bt]);
            acc1[bt] = MFMA16(az, bfr[bt][ks], acc1[bt]);
            accn[bt] = MFMA16(an, bfr[bt][ks], accn[bt]);
          }
        }
      } else {    // B = h ring slot; prefetch all 32 fragments in one volley
        const u16* Bp;
        if (layer == 0) Bp = h0prev;
        else            Bp = iwave ? h0prev : h1prev;
        short8 bfr[4][8];
#pragma unroll
        for (int ks = 0; ks < 8; ++ks)
#pragma unroll
          for (int bt = 0; bt < 4; ++bt)
            bfr[bt][ks] = *(const short8*)(Bp + (size_t)(bt * 16 + lrow) * HID + k0 + ks * 32 + lk8);
#pragma unroll
        for (int ks = 0; ks < 8; ++ks) {
          const int kk = k0 + ks * 32 + lk8;
          const short8 ar = *(const short8*)(Ar + arow + kk);
          const short8 az = *(const short8*)(Az + arow + kk);
          const short8 an = *(const short8*)(An + arow + kk);
#pragma unroll
          for (int bt = 0; bt < 4; ++bt) {
            acc0[bt] = MFMA16(ar, bfr[bt][ks], acc0[bt]);
            acc1[bt] = MFMA16(az, bfr[bt][ks], acc1[bt]);
            accn[bt] = MFMA16(an, bfr[bt][ks], accn[bt]);
          }
        }
      }
      // reduction round 1: i-waves store groups {0,1,2} (XOR-swizzled)
      if (iwave) {
#pragma unroll
        for (int bt = 0; bt < 4; ++bt)
#pragma unroll
          for (int r = 0; r < 4; ++r) {
            const int ix = lane ^ (r << 3);
            lds[(((wv * 4 + 0) * 4 + bt) * 256) + r * 64 + ix] = acc0[bt][r];
            lds[(((wv * 4 + 1) * 4 + bt) * 256) + r * 64 + ix] = acc1[bt][r];
            lds[(((wv * 4 + 2) * 4 + bt) * 256) + r * 64 + ix] = accn[bt][r];
          }
      }
      __syncthreads();
      // reduction round 2: h-waves add groups {0,1}, store group 3
      if (!iwave) {
        const int z = wv - 4;
#pragma unroll
        for (int bt = 0; bt < 4; ++bt)
#pragma unroll
          for (int r = 0; r < 4; ++r) {
            const int ix = lane ^ (r << 3);
            float* q0 = &lds[(((z * 4 + 0) * 4 + bt) * 256) + r * 64 + ix];
            float* q1 = &lds[(((z * 4 + 1) * 4 + bt) * 256) + r * 64 + ix];
            *q0 = *q0 + acc0[bt][r];
            *q1 = *q1 + acc1[bt][r];
            lds[(((z * 4 + 3) * 4 + bt) * 256) + r * 64 + ix] = accn[bt][r];
          }
      }
      __syncthreads();
      // epilogue: gate math (validated), packed 4B relaxed-atomic h-store to ring
      {
        float sr0 = 0.f, sz0 = 0.f, sni0 = 0.f, snh0 = 0.f;
        float sr1 = 0.f, sz1 = 0.f, sni1 = 0.f, snh1 = 0.f;
#pragma unroll
        for (int z = 0; z < 4; ++z) {
          sr0  += lds[(((z * 4 + 0) * 4 + ebt) * 256) + r0 * 64 + ix0];
          sz0  += lds[(((z * 4 + 1) * 4 + ebt) * 256) + r0 * 64 + ix0];
          sni0 += lds[(((z * 4 + 2) * 4 + ebt) * 256) + r0 * 64 + ix0];
          snh0 += lds[(((z * 4 + 3) * 4 + ebt) * 256) + r0 * 64 + ix0];
          sr1  += lds[(((z * 4 + 0) * 4 + ebt) * 256) + r1 * 64 + ix1];
          sz1  += lds[(((z * 4 + 1) * 4 + ebt) * 256) + r1 * 64 + ix1];
          sni1 += lds[(((z * 4 + 2) * 4 + ebt) * 256) + r1 * 64 + ix1];
          snh1 += lds[(((z * 4 + 3) * 4 + ebt) * 256) + r1 * 64 + ix1];
        }
        const float rg0 = sigm(sr0 + bR0);
        const float zg0 = sigm(sz0 + bZ0);
        const float ng0 = tanhf(sni0 + bNi0 + rg0 * (snh0 + bNh0));
        const float hn0 = (1.0f - zg0) * ng0 + zg0 * hp0;
        const float rg1 = sigm(sr1 + bR1);
        const float zg1 = sigm(sz1 + bZ1);
        const float ng1 = tanhf(sni1 + bNi1 + rg1 * (snh1 + bNh1));
        const float hn1 = (1.0f - zg1) * ng1 + zg1 * hp1;
        hp0 = hn0; hp1 = hn1;
        packed = (unsigned)f2b(hn0) | ((unsigned)f2b(hn1) << 16);
        u16* wslot = layer ? (h1r + (size_t)((s - 1) & (R1 - 1)) * SLOT)
                           : (h0r + (size_t)(s & (R0 - 1)) * SLOT);
        __hip_atomic_store((unsigned*)&wslot[eb * HID + eug0], packed,
                           __ATOMIC_RELAXED, __HIP_MEMORY_SCOPE_AGENT);
      }
    }
    // ---- publish: barrier drains ring stores, then flag; h1all AFTER publish ----
    __syncthreads();
    if (tid == 0) {
      unsigned* f = layer ? (p1 + (size_t)(wgid - 64) * 32) : (p0 + (size_t)wgid * 32);
      __hip_atomic_store(f, (unsigned)(s + (layer ? 0 : 1)), __ATOMIC_RELAXED,
                         __HIP_MEMORY_SCOPE_AGENT);
    }
    if (layer)  // streaming store overlaps next step's poll/loads
      *(unsigned*)&h1all[((size_t)(s - 1) * BATCH + eb) * HID + eug0] = packed;
  }
}

// -------- epilogue logits (R5-verified MFMA path, decode-0) --------
__global__ __launch_bounds__(256, 2) void logits_kernel(
    const u16* __restrict__ h1all, const u16* __restrict__ Woutb,
    const float* __restrict__ bout, float* __restrict__ out)
{
  __shared__ __align__(16) short lds[16 * 4 * 64 * 8];
  const int tid = (int)threadIdx.x;
  const int wv = tid >> 6, lane = tid & 63;
  const int lrow = lane & 15, lk8 = (lane >> 4) << 3;
  const int row0 = (int)blockIdx.x * 64 + wv * 16;
  f32x4 acc[16];
#pragma unroll
  for (int i = 0; i < 16; ++i) acc[i] = (f32x4){0.f, 0.f, 0.f, 0.f};

  for (int kc = 0; kc < HID; kc += 128) {
    __syncthreads();
#pragma unroll
    for (int j = 0; j < 16; ++j) {
      const int slot = tid + j * 256;
      const int ct = slot >> 8, kt = (slot >> 6) & 3, l = slot & 63;
      *(short8*)&lds[slot * 8] =
          *(const short8*)(Woutb + (size_t)(ct * 16 + (l & 15)) * HID + kc + kt * 32 + ((l >> 4) << 3));
    }
    __syncthreads();
#pragma unroll
    for (int kt = 0; kt < 4; ++kt) {
      const short8 af = *(const short8*)(h1all + (size_t)(row0 + lrow) * HID + kc + kt * 32 + lk8);
#pragma unroll
      for (int ct = 0; ct < 16; ++ct) {
        const short8 bf = *(const short8*)&lds[((ct * 4 + kt) * 64 + lane) * 8];
        acc[ct] = MFMA16(af, bf, acc[ct]);
      }
    }
  }
#pragma unroll
  for (int ct = 0; ct < 16; ++ct) {
    const int v = ct * 16 + lrow;
    const float bo = bout[v];
#pragma unroll
    for (int r = 0; r < 4; ++r) {
      const int row = row0 + (lane >> 4) * 4 + r;  // row = t*64 + b
      const int t = row >> 6, b = row & 63;
      out[((size_t)(b * T_LEN + t)) * VOC + v] = acc[ct][r] + bo;
    }
  }
}

extern "C" void kernel_launch(void* const* d_in, const int* in_sizes, int n_in,
                              void* d_out, int out_size, void* d_ws, size_t ws_size,
                              hipStream_t stream) {
  const int*   x     = (const int*)d_in[0];
  const float* embed = (const float*)d_in[1];
  const float* Wih0  = (const float*)d_in[2];
  const float* Whh0  = (const float*)d_in[3];
  const float* bih0  = (const float*)d_in[4];
  const float* bhh0  = (const float*)d_in[5];
  const float* Wih1  = (const float*)d_in[6];
  const float* Whh1  = (const float*)d_in[7];
  const float* bih1  = (const float*)d_in[8];
  const float* bhh1  = (const float*)d_in[9];
  const float* Wout  = (const float*)d_in[10];
  const float* bout  = (const float*)d_in[11];
  float* out = (float*)d_out;
  char* ws = (char*)d_ws;
  if (ws_size < (size_t)WS_TOTAL) return;

  // zero: h0 ring slot 255 (h0(-1)=0), h1 ring slot 7 (h1(-1)=0), flags
  hipMemsetAsync(ws + OFF_H0R + (size_t)(R0 - 1) * SLOT * 2, 0, SLOT * 2, stream);
  hipMemsetAsync(ws + OFF_H1R + (size_t)(R1 - 1) * SLOT * 2, 0, SLOT * 2, stream);
  hipMemsetAsync(ws + OFF_SYNC, 0, SYNC_BYTES, stream);
  xt_kernel<<<512, 64, 0, stream>>>(x, (int*)(ws + OFF_XT));
  cvt_kernel<<<128, 256, 0, stream>>>(embed, (u16*)(ws + OFF_EMBT), 256 * 512);
  cvt_kernel<<<1536, 256, 0, stream>>>(Wih0, (u16*)(ws + OFF_WIH0), 3072 * 512);
  cvt_kernel<<<3072, 256, 0, stream>>>(Whh0, (u16*)(ws + OFF_WHH0), 3072 * 1024);
  cvt_kernel<<<3072, 256, 0, stream>>>(Wih1, (u16*)(ws + OFF_WIH1), 3072 * 1024);
  cvt_kernel<<<3072, 256, 0, stream>>>(Whh1, (u16*)(ws + OFF_WHH1), 3072 * 1024);
  cvt_kernel<<<256, 256, 0, stream>>>(Wout, (u16*)(ws + OFF_WOUT), 256 * 1024);

  const u16* wih0b = (const u16*)(ws + OFF_WIH0);
  const u16* whh0b = (const u16*)(ws + OFF_WHH0);
  const u16* wih1b = (const u16*)(ws + OFF_WIH1);
  const u16* whh1b = (const u16*)(ws + OFF_WHH1);

  rnn_persist_kernel<<<NWG, RNN_THREADS, 0, stream>>>(
      (const int*)(ws + OFF_XT), (const u16*)(ws + OFF_EMBT),
      wih0b, wih0b + 524288, wih0b + 1048576,
      whh0b, whh0b + 1048576, whh0b + 2097152,
      wih1b, wih1b + 1048576, wih1b + 2097152,
      whh1b, whh1b + 1048576, whh1b + 2097152,
      bih0, bhh0, bih1, bhh1,
      (u16*)(ws + OFF_H0R), (u16*)(ws + OFF_H1R),
      (u16*)(ws + OFF_H1ALL), (unsigned*)(ws + OFF_SYNC));

  logits_kernel<<<512, 256, 0, stream>>>((const u16*)(ws + OFF_H1ALL),
                                         (const u16*)(ws + OFF_WOUT), bout, out);
}